// Round 9
// baseline (286.135 us; speedup 1.0000x reference)
//
#include <hip/hip_runtime.h>
#include <math.h>

#define NNODES 20000
#define NEDGES 320000
#define RREL 8
#define EPSBN 1e-5f

typedef float f32x4 __attribute__((ext_vector_type(4)));
typedef __bf16 bf16x8 __attribute__((ext_vector_type(8)));
typedef unsigned short u16x8 __attribute__((ext_vector_type(8)));

static __device__ __forceinline__ unsigned short f2bf(float f) {
    unsigned int x = __builtin_bit_cast(unsigned int, f);
    unsigned int r = x + 0x7FFFu + ((x >> 16) & 1u);
    return (unsigned short)(r >> 16);
}
static __device__ __forceinline__ float bf2f(unsigned short u) {
    unsigned int x = ((unsigned int)u) << 16;
    return __builtin_bit_cast(float, x);
}

// async global -> LDS, 16B per lane; LDS dest must be wave-uniform base (lane*16 auto)
static __device__ __forceinline__ void gload16(const unsigned short* g, unsigned short* l) {
    __builtin_amdgcn_global_load_lds((const __attribute__((address_space(1))) unsigned int*)g,
                                     (__attribute__((address_space(3))) unsigned int*)l,
                                     16, 0, 0);
}

// ---------------- CSR build ----------------
__global__ __launch_bounds__(256) void k_count(const int* __restrict__ dst, const int* __restrict__ et,
                                               int* __restrict__ cnt) {
    int e = blockIdx.x * 256 + threadIdx.x;
    if (e >= NEDGES) return;
    atomicAdd(&cnt[dst[e] * RREL + et[e]], 1);
}

__global__ __launch_bounds__(256) void k_invdeg(const int* __restrict__ cnt, float* __restrict__ inv,
                                                int* __restrict__ deg) {
    int i = blockIdx.x * 256 + threadIdx.x;
    if (i >= NNODES) return;
    const int4* p = (const int4*)(cnt + i * 8);
    int4 a = p[0], b = p[1];
    deg[i] = a.x + a.y + a.z + a.w + b.x + b.y + b.z + b.w;
    float4 i0, i1;
    i0.x = 1.0f / (float)(a.x > 0 ? a.x : 1);
    i0.y = 1.0f / (float)(a.y > 0 ? a.y : 1);
    i0.z = 1.0f / (float)(a.z > 0 ? a.z : 1);
    i0.w = 1.0f / (float)(a.w > 0 ? a.w : 1);
    i1.x = 1.0f / (float)(b.x > 0 ? b.x : 1);
    i1.y = 1.0f / (float)(b.y > 0 ? b.y : 1);
    i1.z = 1.0f / (float)(b.z > 0 ? b.z : 1);
    i1.w = 1.0f / (float)(b.w > 0 ? b.w : 1);
    ((float4*)(inv + i * 8))[0] = i0;
    ((float4*)(inv + i * 8))[1] = i1;
}

__global__ __launch_bounds__(256) void k_scan(const int* __restrict__ deg, int* __restrict__ start,
                                              int* __restrict__ cursor) {
    __shared__ int part[256];
    int t = threadIdx.x;
    int i0 = t * 80;
    int s = 0;
    if (i0 < NNODES) {
        for (int i = 0; i < 80; i += 4) {
            int4 v = *(const int4*)(deg + i0 + i);
            s += v.x + v.y + v.z + v.w;
        }
    }
    part[t] = s;
    __syncthreads();
    if (t == 0) {
        int acc = 0;
        for (int j = 0; j < 256; j++) { int v = part[j]; part[j] = acc; acc += v; }
    }
    __syncthreads();
    int acc = part[t];
    if (i0 < NNODES) {
        for (int i = 0; i < 80; i += 4) {
            int4 v = *(const int4*)(deg + i0 + i);
            int4 st;
            st.x = acc; acc += v.x;
            st.y = acc; acc += v.y;
            st.z = acc; acc += v.z;
            st.w = acc; acc += v.w;
            *(int4*)(start + i0 + i) = st;
            *(int4*)(cursor + i0 + i) = st;
        }
    }
}

__global__ __launch_bounds__(256) void k_fill(const int* __restrict__ src, const int* __restrict__ dst,
                                              const int* __restrict__ et, int* __restrict__ cursor,
                                              int* __restrict__ csr) {
    int e = blockIdx.x * 256 + threadIdx.x;
    if (e >= NEDGES) return;
    int pos = atomicAdd(&cursor[dst[e]], 1);
    csr[pos] = src[e] * 8 + et[e];
}

// ---------------- fused prep ----------------
#define PR0 (NNODES * 32)
#define PR1 (2048 * 256)
#define PR2 (256 * 256)
#define PR3 (1024 * 256)
__global__ __launch_bounds__(256) void k_prep(const float* __restrict__ x, const float* __restrict__ Wrel,
                                              const float* __restrict__ Wroot,
                                              const float* __restrict__ Wq, const float* __restrict__ Wk,
                                              const float* __restrict__ Wv, const float* __restrict__ Ws,
                                              const float* __restrict__ bq, const float* __restrict__ bk,
                                              const float* __restrict__ bv, const float* __restrict__ bs,
                                              unsigned short* __restrict__ xb, unsigned short* __restrict__ BrelRoot,
                                              unsigned short* __restrict__ B2t, float* __restrict__ bias2) {
    int i = blockIdx.x * 256 + threadIdx.x;
    if (i < PR0) {
        const float4* p = (const float4*)(x + (size_t)i * 8);
        float4 v0 = p[0], v1 = p[1];
        u16x8 w;
        w[0] = f2bf(v0.x); w[1] = f2bf(v0.y); w[2] = f2bf(v0.z); w[3] = f2bf(v0.w);
        w[4] = f2bf(v1.x); w[5] = f2bf(v1.y); w[6] = f2bf(v1.z); w[7] = f2bf(v1.w);
        *(u16x8*)(xb + (size_t)i * 8) = w;
    } else if (i < PR0 + PR1) {
        int idx = i - PR0;
        int col = idx >> 8, g = idx & 255;
        int r = col >> 8, h = col & 255;
        BrelRoot[idx] = f2bf(Wrel[(size_t)r * 65536 + (size_t)g * 256 + h]);
    } else if (i < PR0 + PR1 + PR2) {
        int idx = i - PR0 - PR1;
        int h = idx >> 8, g = idx & 255;
        BrelRoot[(size_t)2048 * 256 + idx] = f2bf(Wroot[(size_t)g * 256 + h]);
    } else {
        int idx = i - PR0 - PR1 - PR2;
        int c = idx >> 8, g = idx & 255;
        const float* W = (c < 256) ? Wq : (c < 512) ? Wk : (c < 768) ? Wv : Ws;
        int cc = c & 255;
        B2t[idx] = f2bf(W[(size_t)g * 256 + cc]);
        if (g == 0) {
            const float* B = (c < 256) ? bq : (c < 512) ? bk : (c < 768) ? bv : bs;
            bias2[c] = B[cc];
        }
    }
}

// ---------------- bf16 MFMA GEMM v6: m97-style gload_lds staging + coalesced epilogue ----------------
// A[M,256] bf16; Bt[Ncols,256] bf16 pre-transposed. 128x128 tile, 4 waves (64x64 each).
// Linear LDS [128][32] per operand (bank-balanced), global_load_lds width-16 staging,
// single-buffered, 2 barriers/k-iter. bf16 tiles: LDS-bounce epilogue -> 256B-contiguous stores.
// f32 tiles (xroot / skip): direct stores. XCD-bijective swizzle (T1/m204).
// MODE 3: colT<6 -> bf16 C + bias; colT>=6 -> f32 C2 + bias   (QKV | skip)
// MODE 4: colT<16 -> bf16 C; colT>=16 -> f32 C2 + bias         (Yall | xroot+b1)
template<int MODE>
__global__ __launch_bounds__(256) void k_gemm6(const unsigned short* __restrict__ A,
                                               const unsigned short* __restrict__ Bt,
                                               const float* __restrict__ bias,
                                               unsigned short* __restrict__ C, float* __restrict__ C2,
                                               int M, int nct, int q, int rr) {
    __shared__ __align__(16) unsigned short SH[8704];   // staging: As[0..4096) Bs[4096..8192); epilogue: [64][136]
    unsigned short* As = SH;
    unsigned short* Bs = SH + 4096;

    // bijective XCD swizzle
    int bid = blockIdx.x;
    int xcd = bid & 7, idx = bid >> 3;
    int base = (xcd < rr) ? xcd * (q + 1) : rr * (q + 1) + (xcd - rr) * q;
    int nid = base + idx;
    int rowT = nid / nct, colT = nid - rowT * nct;
    int brow = rowT * 128, bcol = colT * 128;

    int tid = threadIdx.x;
    int lane = tid & 63, wid = tid >> 6;
    int wr = wid >> 1, wc = wid & 1;
    int lr = lane & 15, lq = lane >> 4;

    // staging addresses: wave w covers rows w*32..w*32+31 of both tiles (2 calls of 16 rows each)
    int lrow = lane >> 2;            // 0..15
    int lch = (lane & 3) * 8;        // element offset within 32-elem row
    const unsigned short* gA0 = A + (size_t)(brow + wid * 32 + lrow) * 256 + lch;
    const unsigned short* gA1 = gA0 + (size_t)16 * 256;
    const unsigned short* gB0 = Bt + (size_t)(bcol + wid * 32 + lrow) * 256 + lch;
    const unsigned short* gB1 = gB0 + (size_t)16 * 256;
    unsigned short* lA0 = As + (wid * 32) * 32;
    unsigned short* lA1 = As + (wid * 32 + 16) * 32;
    unsigned short* lB0 = Bs + (wid * 32) * 32;
    unsigned short* lB1 = Bs + (wid * 32 + 16) * 32;

    f32x4 acc[4][4];
    #pragma unroll
    for (int i = 0; i < 4; i++)
        #pragma unroll
        for (int j = 0; j < 4; j++) acc[i][j] = (f32x4){0.f, 0.f, 0.f, 0.f};

    for (int ks = 0; ks < 8; ks++) {
        if (ks) __syncthreads();          // prior reads done before DMA overwrite
        gload16(gA0 + ks * 32, lA0);
        gload16(gA1 + ks * 32, lA1);
        gload16(gB0 + ks * 32, lB0);
        gload16(gB1 + ks * 32, lB1);
        __syncthreads();                  // compiler drains vmcnt before barrier: tile ready
        bf16x8 af[4], bfr[4];
        #pragma unroll
        for (int f = 0; f < 4; f++) {
            af[f] = *(const bf16x8*)(As + (wr * 64 + f * 16 + lr) * 32 + lq * 8);
            bfr[f] = *(const bf16x8*)(Bs + (wc * 64 + f * 16 + lr) * 32 + lq * 8);
        }
        #pragma unroll
        for (int i = 0; i < 4; i++)
            #pragma unroll
            for (int j = 0; j < 4; j++)
                acc[i][j] = __builtin_amdgcn_mfma_f32_16x16x32_bf16(af[i], bfr[j], acc[i][j], 0, 0, 0);
    }

    __syncthreads();   // all MFMA LDS reads complete before SH reuse

    bool isF32 = (MODE == 4) ? (colT >= 16) : (colT >= 6);
    if (!isF32) {
        // bias regs (MODE 3 only)
        float bb[4];
        if (MODE == 3) {
            #pragma unroll
            for (int j = 0; j < 4; j++) bb[j] = bias[bcol + wc * 64 + j * 16 + lr];
        }
        const int NC = (MODE == 4) ? 2048 : 768;
        #pragma unroll
        for (int h = 0; h < 2; h++) {
            if (h) __syncthreads();
            if (wr == h) {
                // write this half's acc into SH[64][136] (row-local, bf16)
                #pragma unroll
                for (int i = 0; i < 4; i++)
                    #pragma unroll
                    for (int j = 0; j < 4; j++)
                        #pragma unroll
                        for (int r = 0; r < 4; r++) {
                            int lrow2 = i * 16 + lq * 4 + r;
                            int col = wc * 64 + j * 16 + lr;
                            float v = acc[i][j][r];
                            if (MODE == 3) v += bb[j];
                            SH[lrow2 * 136 + col] = f2bf(v);
                        }
            }
            __syncthreads();
            // stream out: thread t -> row t>>2, 64B chunk (t&3); 256B-contiguous per row
            int row = tid >> 2;
            int ch = (tid & 3) * 32;   // element offset
            int grow = brow + h * 64 + row;
            if (grow < M) {
                unsigned short* dst = C + (size_t)grow * NC + bcol + ch;
                const unsigned short* srcp = SH + row * 136 + ch;
                #pragma unroll
                for (int k = 0; k < 4; k++)
                    *(u16x8*)(dst + k * 8) = *(const u16x8*)(srcp + k * 8);
            }
        }
    } else {
        // f32 direct stores (xroot / skip region)
        #pragma unroll
        for (int i = 0; i < 4; i++) {
            int row = brow + wr * 64 + i * 16 + lq * 4;
            #pragma unroll
            for (int j = 0; j < 4; j++) {
                int col = bcol + wc * 64 + j * 16 + lr;
                #pragma unroll
                for (int r = 0; r < 4; r++) {
                    int gr = row + r;
                    if (gr >= M) continue;
                    float v = acc[i][j][r];
                    if (MODE == 4) C2[(size_t)gr * 256 + (col - 2048)] = v + bias[col - 2048];
                    else           C2[(size_t)gr * 256 + (col - 768)] = v + bias[col];
                }
            }
        }
    }
}

// ---------------- RGCN aggregate + root add, edges batched x8 ----------------
__global__ __launch_bounds__(256) void k_rgcn(const unsigned short* __restrict__ Yall, const int* __restrict__ csr,
                                              const int* __restrict__ start, const int* __restrict__ deg,
                                              const float* __restrict__ inv, const float* __restrict__ xroot,
                                              unsigned short* __restrict__ x1bf) {
    int node = blockIdx.x * 4 + (threadIdx.x >> 6);
    int lane = threadIdx.x & 63;
    if (node >= NNODES) return;
    int s0 = start[node], n = deg[node];
    float4 acc = ((const float4*)(xroot + (size_t)node * 256))[lane];
    int j = 0;
    for (; j + 8 <= n; j += 8) {
        int pk[8];
        #pragma unroll
        for (int t = 0; t < 8; t++) pk[t] = csr[s0 + j + t];
        float cc[8];
        ushort4 yy[8];
        #pragma unroll
        for (int t = 0; t < 8; t++) {
            cc[t] = inv[node * RREL + (pk[t] & 7)];
            yy[t] = *(const ushort4*)(Yall + (size_t)(pk[t] >> 3) * 2048 + (pk[t] & 7) * 256 + lane * 4);
        }
        #pragma unroll
        for (int t = 0; t < 8; t++) {
            acc.x += cc[t] * bf2f(yy[t].x);
            acc.y += cc[t] * bf2f(yy[t].y);
            acc.z += cc[t] * bf2f(yy[t].z);
            acc.w += cc[t] * bf2f(yy[t].w);
        }
    }
    for (; j + 4 <= n; j += 4) {
        int p0 = csr[s0 + j], p1 = csr[s0 + j + 1], p2 = csr[s0 + j + 2], p3 = csr[s0 + j + 3];
        float c0 = inv[node * RREL + (p0 & 7)];
        float c1 = inv[node * RREL + (p1 & 7)];
        float c2 = inv[node * RREL + (p2 & 7)];
        float c3 = inv[node * RREL + (p3 & 7)];
        ushort4 y0 = *(const ushort4*)(Yall + (size_t)(p0 >> 3) * 2048 + (p0 & 7) * 256 + lane * 4);
        ushort4 y1 = *(const ushort4*)(Yall + (size_t)(p1 >> 3) * 2048 + (p1 & 7) * 256 + lane * 4);
        ushort4 y2 = *(const ushort4*)(Yall + (size_t)(p2 >> 3) * 2048 + (p2 & 7) * 256 + lane * 4);
        ushort4 y3 = *(const ushort4*)(Yall + (size_t)(p3 >> 3) * 2048 + (p3 & 7) * 256 + lane * 4);
        acc.x += c0 * bf2f(y0.x) + c1 * bf2f(y1.x) + c2 * bf2f(y2.x) + c3 * bf2f(y3.x);
        acc.y += c0 * bf2f(y0.y) + c1 * bf2f(y1.y) + c2 * bf2f(y2.y) + c3 * bf2f(y3.y);
        acc.z += c0 * bf2f(y0.z) + c1 * bf2f(y1.z) + c2 * bf2f(y2.z) + c3 * bf2f(y3.z);
        acc.w += c0 * bf2f(y0.w) + c1 * bf2f(y1.w) + c2 * bf2f(y2.w) + c3 * bf2f(y3.w);
    }
    for (; j < n; j++) {
        int pk = csr[s0 + j];
        float sc = inv[node * RREL + (pk & 7)];
        ushort4 y = *(const ushort4*)(Yall + (size_t)(pk >> 3) * 2048 + (pk & 7) * 256 + lane * 4);
        acc.x += sc * bf2f(y.x);
        acc.y += sc * bf2f(y.y);
        acc.z += sc * bf2f(y.z);
        acc.w += sc * bf2f(y.w);
    }
    ushort4 o;
    o.x = f2bf(acc.x); o.y = f2bf(acc.y); o.z = f2bf(acc.z); o.w = f2bf(acc.w);
    *(ushort4*)(x1bf + (size_t)node * 256 + lane * 4) = o;
}

// ---------------- fused attention: one wave per node, online softmax, edges batched x4 ----------------
__global__ __launch_bounds__(256) void k_attn(const unsigned short* __restrict__ QKV, const int* __restrict__ csr,
                                              const int* __restrict__ start, const int* __restrict__ deg,
                                              float* __restrict__ out) {
    int node = blockIdx.x * 4 + (threadIdx.x >> 6);
    int lane = threadIdx.x & 63;
    if (node >= NNODES) return;
    int s0 = start[node], n = deg[node];
    if (n == 0) return;
    ushort4 qu = *(const ushort4*)(QKV + (size_t)node * 768 + lane * 4);
    float q0 = bf2f(qu.x), q1 = bf2f(qu.y), q2 = bf2f(qu.z), q3 = bf2f(qu.w);
    float m = -INFINITY, den = 0.f;
    float4 acc = make_float4(0.f, 0.f, 0.f, 0.f);
    int j = 0;
    for (; j + 4 <= n; j += 4) {
        const unsigned short* b0 = QKV + (size_t)(csr[s0 + j] >> 3) * 768;
        const unsigned short* b1 = QKV + (size_t)(csr[s0 + j + 1] >> 3) * 768;
        const unsigned short* b2 = QKV + (size_t)(csr[s0 + j + 2] >> 3) * 768;
        const unsigned short* b3 = QKV + (size_t)(csr[s0 + j + 3] >> 3) * 768;
        ushort4 k0 = *(const ushort4*)(b0 + 256 + lane * 4);
        ushort4 k1 = *(const ushort4*)(b1 + 256 + lane * 4);
        ushort4 k2 = *(const ushort4*)(b2 + 256 + lane * 4);
        ushort4 k3 = *(const ushort4*)(b3 + 256 + lane * 4);
        ushort4 v0 = *(const ushort4*)(b0 + 512 + lane * 4);
        ushort4 v1 = *(const ushort4*)(b1 + 512 + lane * 4);
        ushort4 v2 = *(const ushort4*)(b2 + 512 + lane * 4);
        ushort4 v3 = *(const ushort4*)(b3 + 512 + lane * 4);
        float p0 = q0 * bf2f(k0.x) + q1 * bf2f(k0.y) + q2 * bf2f(k0.z) + q3 * bf2f(k0.w);
        float p1 = q0 * bf2f(k1.x) + q1 * bf2f(k1.y) + q2 * bf2f(k1.z) + q3 * bf2f(k1.w);
        float p2 = q0 * bf2f(k2.x) + q1 * bf2f(k2.y) + q2 * bf2f(k2.z) + q3 * bf2f(k2.w);
        float p3 = q0 * bf2f(k3.x) + q1 * bf2f(k3.y) + q2 * bf2f(k3.z) + q3 * bf2f(k3.w);
        #pragma unroll
        for (int o = 32; o; o >>= 1) {
            p0 += __shfl_xor(p0, o);
            p1 += __shfl_xor(p1, o);
            p2 += __shfl_xor(p2, o);
            p3 += __shfl_xor(p3, o);
        }
        p0 *= 0.0625f; p1 *= 0.0625f; p2 *= 0.0625f; p3 *= 0.0625f;
        float pm = fmaxf(fmaxf(p0, p1), fmaxf(p2, p3));
        if (pm > m) {
            float rr = __expf(m - pm);
            den *= rr;
            acc.x *= rr; acc.y *= rr; acc.z *= rr; acc.w *= rr;
            m = pm;
        }
        float e0 = __expf(p0 - m), e1 = __expf(p1 - m), e2 = __expf(p2 - m), e3 = __expf(p3 - m);
        den += e0 + e1 + e2 + e3;
        acc.x += e0 * bf2f(v0.x) + e1 * bf2f(v1.x) + e2 * bf2f(v2.x) + e3 * bf2f(v3.x);
        acc.y += e0 * bf2f(v0.y) + e1 * bf2f(v1.y) + e2 * bf2f(v2.y) + e3 * bf2f(v3.y);
        acc.z += e0 * bf2f(v0.z) + e1 * bf2f(v1.z) + e2 * bf2f(v2.z) + e3 * bf2f(v3.z);
        acc.w += e0 * bf2f(v0.w) + e1 * bf2f(v1.w) + e2 * bf2f(v2.w) + e3 * bf2f(v3.w);
    }
    for (; j < n; j++) {
        const unsigned short* basep = QKV + (size_t)(csr[s0 + j] >> 3) * 768;
        ushort4 ku = *(const ushort4*)(basep + 256 + lane * 4);
        ushort4 vu = *(const ushort4*)(basep + 512 + lane * 4);
        float p = q0 * bf2f(ku.x) + q1 * bf2f(ku.y) + q2 * bf2f(ku.z) + q3 * bf2f(ku.w);
        #pragma unroll
        for (int o = 32; o; o >>= 1) p += __shfl_xor(p, o);
        p *= 0.0625f;
        if (p > m) {
            float rr = __expf(m - p);
            den *= rr;
            acc.x *= rr; acc.y *= rr; acc.z *= rr; acc.w *= rr;
            m = p;
        }
        float ex = __expf(p - m);
        den += ex;
        acc.x += ex * bf2f(vu.x); acc.y += ex * bf2f(vu.y);
        acc.z += ex * bf2f(vu.z); acc.w += ex * bf2f(vu.w);
    }
    float rinv = 1.0f / fmaxf(den, 1e-16f);
    float4* o4 = (float4*)(out + (size_t)node * 256);
    float4 o = o4[lane];
    o.x += acc.x * rinv; o.y += acc.y * rinv; o.z += acc.z * rinv; o.w += acc.w * rinv;
    o4[lane] = o;
}

// ---------------- batch norm + leaky relu ----------------
__global__ __launch_bounds__(256) void k_bnstats(const float* __restrict__ out, float* __restrict__ sums,
                                                 float* __restrict__ sumsq) {
    int c = threadIdx.x;
    int rows_per = (NNODES + gridDim.x - 1) / gridDim.x;
    int r0 = blockIdx.x * rows_per;
    int r1 = r0 + rows_per; if (r1 > NNODES) r1 = NNODES;
    float s = 0.f, ss = 0.f;
    for (int r = r0; r < r1; r++) {
        float v = out[(size_t)r * 256 + c];
        s += v; ss += v * v;
    }
    atomicAdd(&sums[c], s);
    atomicAdd(&sumsq[c], ss);
}

__global__ __launch_bounds__(256) void k_bnapply(float4* __restrict__ out, const float* __restrict__ sums,
                                                 const float* __restrict__ sumsq, const float* __restrict__ gamma,
                                                 const float* __restrict__ beta) {
    int i = blockIdx.x * 256 + threadIdx.x;
    if (i >= NNODES * 64) return;
    int c4 = i & 63;
    float4 sc, sh;
    #pragma unroll
    for (int t = 0; t < 4; t++) {
        int c = c4 * 4 + t;
        float mu = sums[c] * (1.0f / NNODES);
        float var = sumsq[c] * (1.0f / NNODES) - mu * mu;
        float s = gamma[c] * rsqrtf(fmaxf(var, 0.f) + EPSBN);
        ((float*)&sc)[t] = s;
        ((float*)&sh)[t] = beta[c] - mu * s;
    }
    float4 v = out[i];
    v.x = v.x * sc.x + sh.x; v.y = v.y * sc.y + sh.y;
    v.z = v.z * sc.z + sh.z; v.w = v.w * sc.w + sh.w;
    v.x = v.x > 0.f ? v.x : 0.01f * v.x;
    v.y = v.y > 0.f ? v.y : 0.01f * v.y;
    v.z = v.z > 0.f ? v.z : 0.01f * v.z;
    v.w = v.w > 0.f ? v.w : 0.01f * v.w;
    out[i] = v;
}

extern "C" void kernel_launch(void* const* d_in, const int* in_sizes, int n_in,
                              void* d_out, int out_size, void* d_ws, size_t ws_size,
                              hipStream_t stream) {
    const float* x = (const float*)d_in[0];
    const int* ei = (const int*)d_in[1];
    const int* etype = (const int*)d_in[2];
    const float* Wrel = (const float*)d_in[3];
    const float* Wroot = (const float*)d_in[4];
    const float* b1 = (const float*)d_in[5];
    const float* Wq = (const float*)d_in[6];
    const float* bq = (const float*)d_in[7];
    const float* Wk = (const float*)d_in[8];
    const float* bk = (const float*)d_in[9];
    const float* Wv = (const float*)d_in[10];
    const float* bv = (const float*)d_in[11];
    const float* Ws = (const float*)d_in[12];
    const float* bs = (const float*)d_in[13];
    const float* gamma = (const float*)d_in[14];
    const float* beta = (const float*)d_in[15];
    float* out = (float*)d_out;

    const int* srcA = ei;
    const int* dstA = ei + NEDGES;

    char* w = (char*)d_ws;
    unsigned short* Yall = (unsigned short*)w;  w += (size_t)NNODES * 2048 * 2;
    unsigned short* x_bf = (unsigned short*)w;  w += (size_t)NNODES * 256 * 2;
    unsigned short* x1bf = (unsigned short*)w;  w += (size_t)NNODES * 256 * 2;
    float* xroot = (float*)w;                   w += (size_t)NNODES * 256 * 4;
    unsigned short* QKVbf = (unsigned short*)w; w += (size_t)NNODES * 768 * 2;
    unsigned short* BrelRoot = (unsigned short*)w; w += (size_t)2304 * 256 * 2;
    unsigned short* B2t = (unsigned short*)w;   w += (size_t)1024 * 256 * 2;
    float* bias2 = (float*)w;                   w += 1024 * 4;
    int* cnt = (int*)w;                         w += (size_t)NNODES * RREL * 4;
    float* invc = (float*)w;                    w += (size_t)NNODES * RREL * 4;
    int* deg = (int*)w;                         w += (size_t)NNODES * 4;
    int* startv = (int*)w;                      w += (size_t)NNODES * 4;
    int* cursor = (int*)w;                      w += (size_t)NNODES * 4;
    int* csr = (int*)w;                         w += (size_t)NEDGES * 4;
    float* sums = (float*)w;                    w += 1024;
    float* sumsq = (float*)w;                   w += 1024;
    size_t need = (size_t)(w - (char*)d_ws);
    if (ws_size < need) return;

    hipMemsetAsync(cnt, 0, (size_t)NNODES * RREL * 4, stream);
    hipMemsetAsync(sums, 0, 2048, stream);

    k_count<<<(NEDGES + 255) / 256, 256, 0, stream>>>(dstA, etype, cnt);
    k_invdeg<<<(NNODES + 255) / 256, 256, 0, stream>>>(cnt, invc, deg);
    k_scan<<<1, 256, 0, stream>>>(deg, startv, cursor);
    k_fill<<<(NEDGES + 255) / 256, 256, 0, stream>>>(srcA, dstA, etype, cursor, csr);

    k_prep<<<(PR0 + PR1 + PR2 + PR3) / 256, 256, 0, stream>>>(x, Wrel, Wroot, Wq, Wk, Wv, Ws,
                                                              bq, bk, bv, bs, x_bf, BrelRoot, B2t, bias2);

    // [Yall | xroot+b1] = x_bf @ [W_0..W_7|W_root]; 157 rowT x 18 colT, XCD-swizzled
    {
        int nwg = 157 * 18;
        int q = nwg / 8, rr = nwg % 8;
        k_gemm6<4><<<nwg, 256, 0, stream>>>(x_bf, BrelRoot, b1, Yall, xroot, NNODES, 18, q, rr);
    }

    // x1bf = bf16(xroot + sum_r inv * Yall[src, r])
    k_rgcn<<<(NNODES + 3) / 4, 256, 0, stream>>>(Yall, csr, startv, deg, invc, xroot, x1bf);

    // [q|k|v -> QKVbf, skip -> out] = x1 @ [Wq|Wk|Wv|Wskip] + bias2; 157 x 8, swizzled
    {
        int nwg = 157 * 8;
        int q = nwg / 8, rr = nwg % 8;
        k_gemm6<3><<<nwg, 256, 0, stream>>>(x1bf, B2t, bias2, QKVbf, out, NNODES, 8, q, rr);
    }

    k_attn<<<(NNODES + 3) / 4, 256, 0, stream>>>(QKVbf, csr, startv, deg, out);

    k_bnstats<<<400, 256, 0, stream>>>(out, sums, sumsq);
    k_bnapply<<<(NNODES * 64 + 255) / 256, 256, 0, stream>>>((float4*)out, sums, sumsq, gamma, beta);
}

// Round 10
// 276.240 us; speedup vs baseline: 1.0358x; 1.0358x over previous
//
#include <hip/hip_runtime.h>
#include <math.h>

#define NNODES 20000
#define NEDGES 320000
#define RREL 8
#define EPSBN 1e-5f

typedef float f32x4 __attribute__((ext_vector_type(4)));
typedef __bf16 bf16x8 __attribute__((ext_vector_type(8)));
typedef unsigned short u16x8 __attribute__((ext_vector_type(8)));

static __device__ __forceinline__ unsigned short f2bf(float f) {
    unsigned int x = __builtin_bit_cast(unsigned int, f);
    unsigned int r = x + 0x7FFFu + ((x >> 16) & 1u);
    return (unsigned short)(r >> 16);
}
static __device__ __forceinline__ float bf2f(unsigned short u) {
    unsigned int x = ((unsigned int)u) << 16;
    return __builtin_bit_cast(float, x);
}

// ---------------- CSR build (sorted by (dst, rel)) ----------------
__global__ __launch_bounds__(256) void k_count(const int* __restrict__ dst, const int* __restrict__ et,
                                               int* __restrict__ cnt) {
    int e = blockIdx.x * 256 + threadIdx.x;
    if (e >= NEDGES) return;
    atomicAdd(&cnt[dst[e] * RREL + et[e]], 1);
}

__global__ __launch_bounds__(256) void k_deg(const int* __restrict__ cnt, int* __restrict__ deg) {
    int i = blockIdx.x * 256 + threadIdx.x;
    if (i >= NNODES) return;
    const int4* p = (const int4*)(cnt + i * 8);
    int4 a = p[0], b = p[1];
    deg[i] = a.x + a.y + a.z + a.w + b.x + b.y + b.z + b.w;
}

// single-block exclusive scan over deg -> start
__global__ __launch_bounds__(256) void k_scan(const int* __restrict__ deg, int* __restrict__ start) {
    __shared__ int part[256];
    int t = threadIdx.x;
    int i0 = t * 80;
    int s = 0;
    if (i0 < NNODES) {
        for (int i = 0; i < 80; i += 4) {
            int4 v = *(const int4*)(deg + i0 + i);
            s += v.x + v.y + v.z + v.w;
        }
    }
    part[t] = s;
    __syncthreads();
    if (t == 0) {
        int acc = 0;
        for (int j = 0; j < 256; j++) { int v = part[j]; part[j] = acc; acc += v; }
    }
    __syncthreads();
    int acc = part[t];
    if (i0 < NNODES) {
        for (int i = 0; i < 80; i += 4) {
            int4 v = *(const int4*)(deg + i0 + i);
            int4 st;
            st.x = acc; acc += v.x;
            st.y = acc; acc += v.y;
            st.z = acc; acc += v.z;
            st.w = acc; acc += v.w;
            *(int4*)(start + i0 + i) = st;
        }
    }
}

// per-(node,rel) offsets: start2[d*8+r] = start[d] + prefix(cnt[d][0..r))
__global__ __launch_bounds__(256) void k_sub(const int* __restrict__ cnt, const int* __restrict__ start,
                                             int* __restrict__ start2, int* __restrict__ cursor2) {
    int i = blockIdx.x * 256 + threadIdx.x;
    if (i >= NNODES) return;
    const int4* p = (const int4*)(cnt + i * 8);
    int4 a = p[0], b = p[1];
    int acc = start[i];
    int s2[8];
    s2[0] = acc; acc += a.x;
    s2[1] = acc; acc += a.y;
    s2[2] = acc; acc += a.z;
    s2[3] = acc; acc += a.w;
    s2[4] = acc; acc += b.x;
    s2[5] = acc; acc += b.y;
    s2[6] = acc; acc += b.z;
    s2[7] = acc;
    ((int4*)(start2 + i * 8))[0] = make_int4(s2[0], s2[1], s2[2], s2[3]);
    ((int4*)(start2 + i * 8))[1] = make_int4(s2[4], s2[5], s2[6], s2[7]);
    ((int4*)(cursor2 + i * 8))[0] = make_int4(s2[0], s2[1], s2[2], s2[3]);
    ((int4*)(cursor2 + i * 8))[1] = make_int4(s2[4], s2[5], s2[6], s2[7]);
}

__global__ __launch_bounds__(256) void k_fill(const int* __restrict__ src, const int* __restrict__ dst,
                                              const int* __restrict__ et, int* __restrict__ cursor2,
                                              int* __restrict__ csr) {
    int e = blockIdx.x * 256 + threadIdx.x;
    if (e >= NEDGES) return;
    int pos = atomicAdd(&cursor2[dst[e] * RREL + et[e]], 1);
    csr[pos] = src[e];
}

// ---------------- fused prep: x->bf16, BtA [256][2304], B2t [1024][256] ----------------
#define PR0 (NNODES * 32)
#define PR1 (2048 * 256)
#define PR2 (256 * 256)
#define PR3 (1024 * 256)
__global__ __launch_bounds__(256) void k_prep(const float* __restrict__ x, const float* __restrict__ Wrel,
                                              const float* __restrict__ Wroot,
                                              const float* __restrict__ Wq, const float* __restrict__ Wk,
                                              const float* __restrict__ Wv, const float* __restrict__ Ws,
                                              const float* __restrict__ bq, const float* __restrict__ bk,
                                              const float* __restrict__ bv, const float* __restrict__ bs,
                                              unsigned short* __restrict__ xb, unsigned short* __restrict__ BtA,
                                              unsigned short* __restrict__ B2t, float* __restrict__ bias2) {
    int i = blockIdx.x * 256 + threadIdx.x;
    if (i < PR0) {
        const float4* p = (const float4*)(x + (size_t)i * 8);
        float4 v0 = p[0], v1 = p[1];
        u16x8 w;
        w[0] = f2bf(v0.x); w[1] = f2bf(v0.y); w[2] = f2bf(v0.z); w[3] = f2bf(v0.w);
        w[4] = f2bf(v1.x); w[5] = f2bf(v1.y); w[6] = f2bf(v1.z); w[7] = f2bf(v1.w);
        *(u16x8*)(xb + (size_t)i * 8) = w;
    } else if (i < PR0 + PR1) {
        int idx = i - PR0;
        int h = idx >> 11, k = idx & 2047;       // h: out col, k: rel*256+g
        int r = k >> 8, g = k & 255;
        BtA[(size_t)h * 2304 + k] = f2bf(Wrel[(size_t)r * 65536 + (size_t)g * 256 + h]);
    } else if (i < PR0 + PR1 + PR2) {
        int idx = i - PR0 - PR1;
        int h = idx >> 8, kk = idx & 255;
        BtA[(size_t)h * 2304 + 2048 + kk] = f2bf(Wroot[(size_t)kk * 256 + h]);
    } else {
        int idx = i - PR0 - PR1 - PR2;
        int c = idx >> 8, g = idx & 255;
        const float* W = (c < 256) ? Wq : (c < 512) ? Wk : (c < 768) ? Wv : Ws;
        int cc = c & 255;
        B2t[(size_t)c * 256 + g] = f2bf(W[(size_t)g * 256 + cc]);
        if (g == 0) {
            const float* B = (c < 256) ? bq : (c < 512) ? bk : (c < 768) ? bv : bs;
            bias2[c] = B[cc];
        }
    }
}

// ---------------- mean-gather: S[d] = [mean_r(x) r=0..7 | x], bf16 ----------------
__global__ __launch_bounds__(256) void k_mean(const unsigned short* __restrict__ xb, const int* __restrict__ csr,
                                              const int* __restrict__ start2, const int* __restrict__ cnt,
                                              unsigned short* __restrict__ S) {
    int node = blockIdx.x * 4 + (threadIdx.x >> 6);
    int lane = threadIdx.x & 63;
    if (node >= NNODES) return;
    // copy x row into cols 2048..2303
    ushort4 xr = *(const ushort4*)(xb + (size_t)node * 256 + lane * 4);
    *(ushort4*)(S + (size_t)node * 2304 + 2048 + lane * 4) = xr;
    int base = node * 8;
    for (int r = 0; r < 8; r++) {
        int s0 = start2[base + r];
        int n = cnt[base + r];
        float4 acc = make_float4(0.f, 0.f, 0.f, 0.f);
        int j = 0;
        for (; j + 2 <= n; j += 2) {
            int sa = csr[s0 + j], sb = csr[s0 + j + 1];
            ushort4 ya = *(const ushort4*)(xb + (size_t)sa * 256 + lane * 4);
            ushort4 yb = *(const ushort4*)(xb + (size_t)sb * 256 + lane * 4);
            acc.x += bf2f(ya.x) + bf2f(yb.x);
            acc.y += bf2f(ya.y) + bf2f(yb.y);
            acc.z += bf2f(ya.z) + bf2f(yb.z);
            acc.w += bf2f(ya.w) + bf2f(yb.w);
        }
        if (j < n) {
            int sa = csr[s0 + j];
            ushort4 ya = *(const ushort4*)(xb + (size_t)sa * 256 + lane * 4);
            acc.x += bf2f(ya.x);
            acc.y += bf2f(ya.y);
            acc.z += bf2f(ya.z);
            acc.w += bf2f(ya.w);
        }
        float sc = 1.0f / (float)(n > 0 ? n : 1);
        ushort4 o;
        o.x = f2bf(acc.x * sc); o.y = f2bf(acc.y * sc);
        o.z = f2bf(acc.z * sc); o.w = f2bf(acc.w * sc);
        *(ushort4*)(S + (size_t)node * 2304 + r * 256 + lane * 4) = o;
    }
}

// ---------------- bf16 MFMA GEMM v7: v5 reg-staged core + LDS-bounce bf16 epilogue ----------------
// A[M,K] bf16; Bt[Ncols][K] bf16 pre-transposed. 128x128 tile, 4 waves (64x64 each).
// Padded LDS [128][40], reg double-buffer staging, 2 barriers/k-iter. XCD-bijective swizzle.
// MODE 5: bf16 out = acc + bias (x1bf, NC=256)
// MODE 3: colT<6 -> bf16 QKV + bias (NC=768); colT>=6 -> f32 skip C2 + bias (direct)
template<int MODE>
__global__ __launch_bounds__(256) void k_gemm7(const unsigned short* __restrict__ A,
                                               const unsigned short* __restrict__ Bt,
                                               const float* __restrict__ bias,
                                               unsigned short* __restrict__ C, float* __restrict__ C2,
                                               int M, int K, int nct, int q, int rr) {
    __shared__ __align__(16) unsigned short SH[10240];   // staging 2x[128][40]; epilogue bounce [64][136]
    unsigned short* As = SH;
    unsigned short* Bs = SH + 5120;

    int bid = blockIdx.x;
    int xcd = bid & 7, idx = bid >> 3;
    int base = (xcd < rr) ? xcd * (q + 1) : rr * (q + 1) + (xcd - rr) * q;
    int nid = base + idx;
    int rowT = nid / nct, colT = nid - rowT * nct;
    int brow = rowT * 128, bcol = colT * 128;

    int tid = threadIdx.x;
    int lane = tid & 63, wid = tid >> 6;
    int wr = wid >> 1, wc = wid & 1;
    int lr = lane & 15, lq = lane >> 4;

    int srow = tid >> 1;
    int sseg = (tid & 1) * 16;
    const unsigned short* gA = A + (size_t)(brow + srow) * K + sseg;
    const unsigned short* gB = Bt + (size_t)(bcol + srow) * K + sseg;
    bool aok = (brow + srow) < M;
    const u16x8 zz = {0, 0, 0, 0, 0, 0, 0, 0};

    u16x8 ra0 = aok ? *(const u16x8*)(gA) : zz;
    u16x8 ra1 = aok ? *(const u16x8*)(gA + 8) : zz;
    u16x8 rb0 = *(const u16x8*)(gB);
    u16x8 rb1 = *(const u16x8*)(gB + 8);

    f32x4 acc[4][4];
    #pragma unroll
    for (int i = 0; i < 4; i++)
        #pragma unroll
        for (int j = 0; j < 4; j++) acc[i][j] = (f32x4){0.f, 0.f, 0.f, 0.f};

    int nk = K >> 5;
    for (int ks = 0; ks < nk; ks++) {
        if (ks) __syncthreads();
        *(u16x8*)(As + srow * 40 + sseg) = ra0;
        *(u16x8*)(As + srow * 40 + sseg + 8) = ra1;
        *(u16x8*)(Bs + srow * 40 + sseg) = rb0;
        *(u16x8*)(Bs + srow * 40 + sseg + 8) = rb1;
        __syncthreads();
        if (ks + 1 < nk) {
            const unsigned short* pa = gA + (ks + 1) * 32;
            const unsigned short* pb = gB + (ks + 1) * 32;
            ra0 = aok ? *(const u16x8*)(pa) : zz;
            ra1 = aok ? *(const u16x8*)(pa + 8) : zz;
            rb0 = *(const u16x8*)(pb);
            rb1 = *(const u16x8*)(pb + 8);
        }
        bf16x8 af[4], bfr[4];
        #pragma unroll
        for (int f = 0; f < 4; f++) {
            af[f] = *(const bf16x8*)(As + (wr * 64 + f * 16 + lr) * 40 + lq * 8);
            bfr[f] = *(const bf16x8*)(Bs + (wc * 64 + f * 16 + lr) * 40 + lq * 8);
        }
        #pragma unroll
        for (int i = 0; i < 4; i++)
            #pragma unroll
            for (int j = 0; j < 4; j++)
                acc[i][j] = __builtin_amdgcn_mfma_f32_16x16x32_bf16(af[i], bfr[j], acc[i][j], 0, 0, 0);
    }

    __syncthreads();   // MFMA LDS reads complete before SH reuse

    bool bf16out = (MODE == 5) || (colT < 6);
    if (bf16out) {
        float bb[4];
        #pragma unroll
        for (int j = 0; j < 4; j++) bb[j] = bias[bcol + wc * 64 + j * 16 + lr];
        const int NC = (MODE == 5) ? 256 : 768;
        #pragma unroll
        for (int h = 0; h < 2; h++) {
            if (h) __syncthreads();
            if (wr == h) {
                #pragma unroll
                for (int i = 0; i < 4; i++)
                    #pragma unroll
                    for (int j = 0; j < 4; j++)
                        #pragma unroll
                        for (int r = 0; r < 4; r++) {
                            int lrow2 = i * 16 + lq * 4 + r;
                            int col = wc * 64 + j * 16 + lr;
                            SH[lrow2 * 136 + col] = f2bf(acc[i][j][r] + bb[j]);
                        }
            }
            __syncthreads();
            int row = tid >> 2;
            int ch = (tid & 3) * 32;
            int grow = brow + h * 64 + row;
            if (grow < M) {
                unsigned short* dstp = C + (size_t)grow * NC + bcol + ch;
                const unsigned short* srcp = SH + row * 136 + ch;
                #pragma unroll
                for (int k = 0; k < 4; k++)
                    *(u16x8*)(dstp + k * 8) = *(const u16x8*)(srcp + k * 8);
            }
        }
    } else {
        // f32 skip region (MODE 3, cols 768..1023)
        #pragma unroll
        for (int i = 0; i < 4; i++) {
            int row = brow + wr * 64 + i * 16 + lq * 4;
            #pragma unroll
            for (int j = 0; j < 4; j++) {
                int col = bcol + wc * 64 + j * 16 + lr;
                #pragma unroll
                for (int r = 0; r < 4; r++) {
                    int gr = row + r;
                    if (gr >= M) continue;
                    C2[(size_t)gr * 256 + (col - 768)] = acc[i][j][r] + bias[col];
                }
            }
        }
    }
}

// ---------------- fused attention: one wave per node, online softmax, edges batched x4 ----------------
__global__ __launch_bounds__(256) void k_attn(const unsigned short* __restrict__ QKV, const int* __restrict__ csr,
                                              const int* __restrict__ start2, const int* __restrict__ deg,
                                              float* __restrict__ out) {
    int node = blockIdx.x * 4 + (threadIdx.x >> 6);
    int lane = threadIdx.x & 63;
    if (node >= NNODES) return;
    int s0 = start2[node * 8], n = deg[node];
    if (n == 0) return;
    ushort4 qu = *(const ushort4*)(QKV + (size_t)node * 768 + lane * 4);
    float q0 = bf2f(qu.x), q1 = bf2f(qu.y), q2 = bf2f(qu.z), q3 = bf2f(qu.w);
    float m = -INFINITY, den = 0.f;
    float4 acc = make_float4(0.f, 0.f, 0.f, 0.f);
    int j = 0;
    for (; j + 4 <= n; j += 4) {
        const unsigned short* b0 = QKV + (size_t)csr[s0 + j] * 768;
        const unsigned short* b1 = QKV + (size_t)csr[s0 + j + 1] * 768;
        const unsigned short* b2 = QKV + (size_t)csr[s0 + j + 2] * 768;
        const unsigned short* b3 = QKV + (size_t)csr[s0 + j + 3] * 768;
        ushort4 k0 = *(const ushort4*)(b0 + 256 + lane * 4);
        ushort4 k1 = *(const ushort4*)(b1 + 256 + lane * 4);
        ushort4 k2 = *(const ushort4*)(b2 + 256 + lane * 4);
        ushort4 k3 = *(const ushort4*)(b3 + 256 + lane * 4);
        ushort4 v0 = *(const ushort4*)(b0 + 512 + lane * 4);
        ushort4 v1 = *(const ushort4*)(b1 + 512 + lane * 4);
        ushort4 v2 = *(const ushort4*)(b2 + 512 + lane * 4);
        ushort4 v3 = *(const ushort4*)(b3 + 512 + lane * 4);
        float p0 = q0 * bf2f(k0.x) + q1 * bf2f(k0.y) + q2 * bf2f(k0.z) + q3 * bf2f(k0.w);
        float p1 = q0 * bf2f(k1.x) + q1 * bf2f(k1.y) + q2 * bf2f(k1.z) + q3 * bf2f(k1.w);
        float p2 = q0 * bf2f(k2.x) + q1 * bf2f(k2.y) + q2 * bf2f(k2.z) + q3 * bf2f(k2.w);
        float p3 = q0 * bf2f(k3.x) + q1 * bf2f(k3.y) + q2 * bf2f(k3.z) + q3 * bf2f(k3.w);
        #pragma unroll
        for (int o = 32; o; o >>= 1) {
            p0 += __shfl_xor(p0, o);
            p1 += __shfl_xor(p1, o);
            p2 += __shfl_xor(p2, o);
            p3 += __shfl_xor(p3, o);
        }
        p0 *= 0.0625f; p1 *= 0.0625f; p2 *= 0.0625f; p3 *= 0.0625f;
        float pm = fmaxf(fmaxf(p0, p1), fmaxf(p2, p3));
        if (pm > m) {
            float rr = __expf(m - pm);
            den *= rr;
            acc.x *= rr; acc.y *= rr; acc.z *= rr; acc.w *= rr;
            m = pm;
        }
        float e0 = __expf(p0 - m), e1 = __expf(p1 - m), e2 = __expf(p2 - m), e3 = __expf(p3 - m);
        den += e0 + e1 + e2 + e3;
        acc.x += e0 * bf2f(v0.x) + e1 * bf2f(v1.x) + e2 * bf2f(v2.x) + e3 * bf2f(v3.x);
        acc.y += e0 * bf2f(v0.y) + e1 * bf2f(v1.y) + e2 * bf2f(v2.y) + e3 * bf2f(v3.y);
        acc.z += e0 * bf2f(v0.z) + e1 * bf2f(v1.z) + e2 * bf2f(v2.z) + e3 * bf2f(v3.z);
        acc.w += e0 * bf2f(v0.w) + e1 * bf2f(v1.w) + e2 * bf2f(v2.w) + e3 * bf2f(v3.w);
    }
    for (; j < n; j++) {
        const unsigned short* basep = QKV + (size_t)csr[s0 + j] * 768;
        ushort4 ku = *(const ushort4*)(basep + 256 + lane * 4);
        ushort4 vu = *(const ushort4*)(basep + 512 + lane * 4);
        float p = q0 * bf2f(ku.x) + q1 * bf2f(ku.y) + q2 * bf2f(ku.z) + q3 * bf2f(ku.w);
        #pragma unroll
        for (int o = 32; o; o >>= 1) p += __shfl_xor(p, o);
        p *= 0.0625f;
        if (p > m) {
            float rr = __expf(m - p);
            den *= rr;
            acc.x *= rr; acc.y *= rr; acc.z *= rr; acc.w *= rr;
            m = p;
        }
        float ex = __expf(p - m);
        den += ex;
        acc.x += ex * bf2f(vu.x); acc.y += ex * bf2f(vu.y);
        acc.z += ex * bf2f(vu.z); acc.w += ex * bf2f(vu.w);
    }
    float rinv = 1.0f / fmaxf(den, 1e-16f);
    float4* o4 = (float4*)(out + (size_t)node * 256);
    float4 o = o4[lane];
    o.x += acc.x * rinv; o.y += acc.y * rinv; o.z += acc.z * rinv; o.w += acc.w * rinv;
    o4[lane] = o;
}

// ---------------- batch norm + leaky relu ----------------
__global__ __launch_bounds__(256) void k_bnstats(const float* __restrict__ out, float* __restrict__ sums,
                                                 float* __restrict__ sumsq) {
    int c = threadIdx.x;
    int rows_per = (NNODES + gridDim.x - 1) / gridDim.x;
    int r0 = blockIdx.x * rows_per;
    int r1 = r0 + rows_per; if (r1 > NNODES) r1 = NNODES;
    float s = 0.f, ss = 0.f;
    for (int r = r0; r < r1; r++) {
        float v = out[(size_t)r * 256 + c];
        s += v; ss += v * v;
    }
    atomicAdd(&sums[c], s);
    atomicAdd(&sumsq[c], ss);
}

__global__ __launch_bounds__(256) void k_bnapply(float4* __restrict__ out, const float* __restrict__ sums,
                                                 const float* __restrict__ sumsq, const float* __restrict__ gamma,
                                                 const float* __restrict__ beta) {
    int i = blockIdx.x * 256 + threadIdx.x;
    if (i >= NNODES * 64) return;
    int c4 = i & 63;
    float4 sc, sh;
    #pragma unroll
    for (int t = 0; t < 4; t++) {
        int c = c4 * 4 + t;
        float mu = sums[c] * (1.0f / NNODES);
        float var = sumsq[c] * (1.0f / NNODES) - mu * mu;
        float s = gamma[c] * rsqrtf(fmaxf(var, 0.f) + EPSBN);
        ((float*)&sc)[t] = s;
        ((float*)&sh)[t] = beta[c] - mu * s;
    }
    float4 v = out[i];
    v.x = v.x * sc.x + sh.x; v.y = v.y * sc.y + sh.y;
    v.z = v.z * sc.z + sh.z; v.w = v.w * sc.w + sh.w;
    v.x = v.x > 0.f ? v.x : 0.01f * v.x;
    v.y = v.y > 0.f ? v.y : 0.01f * v.y;
    v.z = v.z > 0.f ? v.z : 0.01f * v.z;
    v.w = v.w > 0.f ? v.w : 0.01f * v.w;
    out[i] = v;
}

extern "C" void kernel_launch(void* const* d_in, const int* in_sizes, int n_in,
                              void* d_out, int out_size, void* d_ws, size_t ws_size,
                              hipStream_t stream) {
    const float* x = (const float*)d_in[0];
    const int* ei = (const int*)d_in[1];
    const int* etype = (const int*)d_in[2];
    const float* Wrel = (const float*)d_in[3];
    const float* Wroot = (const float*)d_in[4];
    const float* b1 = (const float*)d_in[5];
    const float* Wq = (const float*)d_in[6];
    const float* bq = (const float*)d_in[7];
    const float* Wk = (const float*)d_in[8];
    const float* bk = (const float*)d_in[9];
    const float* Wv = (const float*)d_in[10];
    const float* bv = (const float*)d_in[11];
    const float* Ws = (const float*)d_in[12];
    const float* bs = (const float*)d_in[13];
    const float* gamma = (const float*)d_in[14];
    const float* beta = (const float*)d_in[15];
    float* out = (float*)d_out;

    const int* srcA = ei;
    const int* dstA = ei + NEDGES;

    char* w = (char*)d_ws;
    unsigned short* S = (unsigned short*)w;     w += (size_t)NNODES * 2304 * 2;  // 92.2 MB
    unsigned short* x_bf = (unsigned short*)w;  w += (size_t)NNODES * 256 * 2;   // 10.2 MB
    unsigned short* x1bf = (unsigned short*)w;  w += (size_t)NNODES * 256 * 2;   // 10.2 MB
    unsigned short* QKVbf = (unsigned short*)w; w += (size_t)NNODES * 768 * 2;   // 30.7 MB
    unsigned short* BtA = (unsigned short*)w;   w += (size_t)256 * 2304 * 2;     //  1.2 MB
    unsigned short* B2t = (unsigned short*)w;   w += (size_t)1024 * 256 * 2;
    float* bias2 = (float*)w;                   w += 1024 * 4;
    int* cnt = (int*)w;                         w += (size_t)NNODES * RREL * 4;
    int* deg = (int*)w;                         w += (size_t)NNODES * 4;
    int* startv = (int*)w;                      w += (size_t)NNODES * 4;
    int* start2 = (int*)w;                      w += (size_t)NNODES * RREL * 4;
    int* cursor2 = (int*)w;                     w += (size_t)NNODES * RREL * 4;
    int* csr = (int*)w;                         w += (size_t)NEDGES * 4;
    float* sums = (float*)w;                    w += 1024;
    float* sumsq = (float*)w;                   w += 1024;
    size_t need = (size_t)(w - (char*)d_ws);
    if (ws_size < need) return;

    hipMemsetAsync(cnt, 0, (size_t)NNODES * RREL * 4, stream);
    hipMemsetAsync(sums, 0, 2048, stream);

    k_count<<<(NEDGES + 255) / 256, 256, 0, stream>>>(dstA, etype, cnt);
    k_deg<<<(NNODES + 255) / 256, 256, 0, stream>>>(cnt, deg);
    k_scan<<<1, 256, 0, stream>>>(deg, startv);
    k_sub<<<(NNODES + 255) / 256, 256, 0, stream>>>(cnt, startv, start2, cursor2);
    k_fill<<<(NEDGES + 255) / 256, 256, 0, stream>>>(srcA, dstA, etype, cursor2, csr);

    k_prep<<<(PR0 + PR1 + PR2 + PR3) / 256, 256, 0, stream>>>(x, Wrel, Wroot, Wq, Wk, Wv, Ws,
                                                              bq, bk, bv, bs, x_bf, BtA, B2t, bias2);

    // S[d] = [mean_r(x) | x] (bf16), gather from L2-resident x_bf
    k_mean<<<(NNODES + 3) / 4, 256, 0, stream>>>(x_bf, csr, start2, cnt, S);

    // x1bf = bf16(S @ [W_0..W_7; W_root] + b1); K=2304, 157x2 tiles, XCD-swizzled
    {
        int nwg = 157 * 2;
        int q = nwg / 8, rr = nwg % 8;
        k_gemm7<5><<<nwg, 256, 0, stream>>>(S, BtA, b1, x1bf, nullptr, NNODES, 2304, 2, q, rr);
    }

    // [q|k|v -> QKVbf, skip -> out] = x1 @ [Wq|Wk|Wv|Wskip] + bias2; K=256, 157x8, swizzled
    {
        int nwg = 157 * 8;
        int q = nwg / 8, rr = nwg % 8;
        k_gemm7<3><<<nwg, 256, 0, stream>>>(x1bf, B2t, bias2, QKVbf, out, NNODES, 256, 8, q, rr);
    }

    k_attn<<<(NNODES + 3) / 4, 256, 0, stream>>>(QKVbf, csr, start2, deg, out);

    k_bnstats<<<400, 256, 0, stream>>>(out, sums, sumsq);
    k_bnapply<<<(NNODES * 64 + 255) / 256, 256, 0, stream>>>((float4*)out, sums, sumsq, gamma, beta);
}

// Round 11
// 275.116 us; speedup vs baseline: 1.0401x; 1.0041x over previous
//
#include <hip/hip_runtime.h>
#include <math.h>

#define NNODES 20000
#define NEDGES 320000
#define RREL 8
#define EPSBN 1e-5f

typedef float f32x4 __attribute__((ext_vector_type(4)));
typedef __bf16 bf16x8 __attribute__((ext_vector_type(8)));
typedef unsigned short u16x8 __attribute__((ext_vector_type(8)));

static __device__ __forceinline__ unsigned short f2bf(float f) {
    unsigned int x = __builtin_bit_cast(unsigned int, f);
    unsigned int r = x + 0x7FFFu + ((x >> 16) & 1u);
    return (unsigned short)(r >> 16);
}
static __device__ __forceinline__ float bf2f(unsigned short u) {
    unsigned int x = ((unsigned int)u) << 16;
    return __builtin_bit_cast(float, x);
}

// ---------------- CSR build (sorted by (dst, rel)) ----------------
__global__ __launch_bounds__(256) void k_count(const int* __restrict__ dst, const int* __restrict__ et,
                                               int* __restrict__ cnt) {
    int e = blockIdx.x * 256 + threadIdx.x;
    if (e >= NEDGES) return;
    atomicAdd(&cnt[dst[e] * RREL + et[e]], 1);
}

__global__ __launch_bounds__(256) void k_deg(const int* __restrict__ cnt, int* __restrict__ deg) {
    int i = blockIdx.x * 256 + threadIdx.x;
    if (i >= NNODES) return;
    const int4* p = (const int4*)(cnt + i * 8);
    int4 a = p[0], b = p[1];
    deg[i] = a.x + a.y + a.z + a.w + b.x + b.y + b.z + b.w;
}

__global__ __launch_bounds__(256) void k_scan(const int* __restrict__ deg, int* __restrict__ start) {
    __shared__ int part[256];
    int t = threadIdx.x;
    int i0 = t * 80;
    int s = 0;
    if (i0 < NNODES) {
        for (int i = 0; i < 80; i += 4) {
            int4 v = *(const int4*)(deg + i0 + i);
            s += v.x + v.y + v.z + v.w;
        }
    }
    part[t] = s;
    __syncthreads();
    if (t == 0) {
        int acc = 0;
        for (int j = 0; j < 256; j++) { int v = part[j]; part[j] = acc; acc += v; }
    }
    __syncthreads();
    int acc = part[t];
    if (i0 < NNODES) {
        for (int i = 0; i < 80; i += 4) {
            int4 v = *(const int4*)(deg + i0 + i);
            int4 st;
            st.x = acc; acc += v.x;
            st.y = acc; acc += v.y;
            st.z = acc; acc += v.z;
            st.w = acc; acc += v.w;
            *(int4*)(start + i0 + i) = st;
        }
    }
}

__global__ __launch_bounds__(256) void k_sub(const int* __restrict__ cnt, const int* __restrict__ start,
                                             int* __restrict__ start2, int* __restrict__ cursor2) {
    int i = blockIdx.x * 256 + threadIdx.x;
    if (i >= NNODES) return;
    const int4* p = (const int4*)(cnt + i * 8);
    int4 a = p[0], b = p[1];
    int acc = start[i];
    int s2[8];
    s2[0] = acc; acc += a.x;
    s2[1] = acc; acc += a.y;
    s2[2] = acc; acc += a.z;
    s2[3] = acc; acc += a.w;
    s2[4] = acc; acc += b.x;
    s2[5] = acc; acc += b.y;
    s2[6] = acc; acc += b.z;
    s2[7] = acc;
    ((int4*)(start2 + i * 8))[0] = make_int4(s2[0], s2[1], s2[2], s2[3]);
    ((int4*)(start2 + i * 8))[1] = make_int4(s2[4], s2[5], s2[6], s2[7]);
    ((int4*)(cursor2 + i * 8))[0] = make_int4(s2[0], s2[1], s2[2], s2[3]);
    ((int4*)(cursor2 + i * 8))[1] = make_int4(s2[4], s2[5], s2[6], s2[7]);
}

__global__ __launch_bounds__(256) void k_fill(const int* __restrict__ src, const int* __restrict__ dst,
                                              const int* __restrict__ et, int* __restrict__ cursor2,
                                              int* __restrict__ csr) {
    int e = blockIdx.x * 256 + threadIdx.x;
    if (e >= NEDGES) return;
    int pos = atomicAdd(&cursor2[dst[e] * RREL + et[e]], 1);
    csr[pos] = src[e];
}

// ---------------- fused prep: x->bf16, BtA [256][2304], B2t [1024][256] ----------------
#define PR0 (NNODES * 32)
#define PR1 (2048 * 256)
#define PR2 (256 * 256)
#define PR3 (1024 * 256)
__global__ __launch_bounds__(256) void k_prep(const float* __restrict__ x, const float* __restrict__ Wrel,
                                              const float* __restrict__ Wroot,
                                              const float* __restrict__ Wq, const float* __restrict__ Wk,
                                              const float* __restrict__ Wv, const float* __restrict__ Ws,
                                              const float* __restrict__ bq, const float* __restrict__ bk,
                                              const float* __restrict__ bv, const float* __restrict__ bs,
                                              unsigned short* __restrict__ xb, unsigned short* __restrict__ BtA,
                                              unsigned short* __restrict__ B2t, float* __restrict__ bias2) {
    int i = blockIdx.x * 256 + threadIdx.x;
    if (i < PR0) {
        const float4* p = (const float4*)(x + (size_t)i * 8);
        float4 v0 = p[0], v1 = p[1];
        u16x8 w;
        w[0] = f2bf(v0.x); w[1] = f2bf(v0.y); w[2] = f2bf(v0.z); w[3] = f2bf(v0.w);
        w[4] = f2bf(v1.x); w[5] = f2bf(v1.y); w[6] = f2bf(v1.z); w[7] = f2bf(v1.w);
        *(u16x8*)(xb + (size_t)i * 8) = w;
    } else if (i < PR0 + PR1) {
        int idx = i - PR0;
        int h = idx >> 11, k = idx & 2047;
        int r = k >> 8, g = k & 255;
        BtA[(size_t)h * 2304 + k] = f2bf(Wrel[(size_t)r * 65536 + (size_t)g * 256 + h]);
    } else if (i < PR0 + PR1 + PR2) {
        int idx = i - PR0 - PR1;
        int h = idx >> 8, kk = idx & 255;
        BtA[(size_t)h * 2304 + 2048 + kk] = f2bf(Wroot[(size_t)kk * 256 + h]);
    } else {
        int idx = i - PR0 - PR1 - PR2;
        int c = idx >> 8, g = idx & 255;
        const float* W = (c < 256) ? Wq : (c < 512) ? Wk : (c < 768) ? Wv : Ws;
        int cc = c & 255;
        B2t[(size_t)c * 256 + g] = f2bf(W[(size_t)g * 256 + cc]);
        if (g == 0) {
            const float* B = (c < 256) ? bq : (c < 512) ? bk : (c < 768) ? bv : bs;
            bias2[c] = B[cc];
        }
    }
}

// ---------------- mean-gather: S[d] = [mean_r(x) r=0..7 | x], bf16 ----------------
__global__ __launch_bounds__(256) void k_mean(const unsigned short* __restrict__ xb, const int* __restrict__ csr,
                                              const int* __restrict__ start2, const int* __restrict__ cnt,
                                              unsigned short* __restrict__ S) {
    int node = blockIdx.x * 4 + (threadIdx.x >> 6);
    int lane = threadIdx.x & 63;
    if (node >= NNODES) return;
    ushort4 xr = *(const ushort4*)(xb + (size_t)node * 256 + lane * 4);
    *(ushort4*)(S + (size_t)node * 2304 + 2048 + lane * 4) = xr;
    int base = node * 8;
    for (int r = 0; r < 8; r++) {
        int s0 = start2[base + r];
        int n = cnt[base + r];
        float4 acc = make_float4(0.f, 0.f, 0.f, 0.f);
        int j = 0;
        for (; j + 2 <= n; j += 2) {
            int sa = csr[s0 + j], sb = csr[s0 + j + 1];
            ushort4 ya = *(const ushort4*)(xb + (size_t)sa * 256 + lane * 4);
            ushort4 yb = *(const ushort4*)(xb + (size_t)sb * 256 + lane * 4);
            acc.x += bf2f(ya.x) + bf2f(yb.x);
            acc.y += bf2f(ya.y) + bf2f(yb.y);
            acc.z += bf2f(ya.z) + bf2f(yb.z);
            acc.w += bf2f(ya.w) + bf2f(yb.w);
        }
        if (j < n) {
            int sa = csr[s0 + j];
            ushort4 ya = *(const ushort4*)(xb + (size_t)sa * 256 + lane * 4);
            acc.x += bf2f(ya.x);
            acc.y += bf2f(ya.y);
            acc.z += bf2f(ya.z);
            acc.w += bf2f(ya.w);
        }
        float sc = 1.0f / (float)(n > 0 ? n : 1);
        ushort4 o;
        o.x = f2bf(acc.x * sc); o.y = f2bf(acc.y * sc);
        o.z = f2bf(acc.z * sc); o.w = f2bf(acc.w * sc);
        *(ushort4*)(S + (size_t)node * 2304 + r * 256 + lane * 4) = o;
    }
}

// ---------------- GEMM v8: 64x128 tile (grid-fill for K=2304, N=256) ----------------
// A[M,K] bf16; Bt[256][K] bf16. 4 waves, each 32x64 out (2x4 frags, 8 MFMA/kstep).
// Reg-staged, padded LDS, 2 barriers/k-iter; bf16 bounce epilogue; XCD-bijective swizzle.
__global__ __launch_bounds__(256) void k_gemm8(const unsigned short* __restrict__ A,
                                               const unsigned short* __restrict__ Bt,
                                               const float* __restrict__ bias,
                                               unsigned short* __restrict__ C,
                                               int M, int K, int nct, int q, int rr) {
    __shared__ __align__(16) unsigned short SH[8704];   // staging A[64][40]+B[128][40]=7680; bounce [64][136]
    unsigned short* As = SH;
    unsigned short* Bs = SH + 64 * 40;

    int bid = blockIdx.x;
    int xcd = bid & 7, idx = bid >> 3;
    int base = (xcd < rr) ? xcd * (q + 1) : rr * (q + 1) + (xcd - rr) * q;
    int nid = base + idx;
    int rowT = nid / nct, colT = nid - rowT * nct;
    int brow = rowT * 64, bcol = colT * 128;

    int tid = threadIdx.x;
    int lane = tid & 63, wid = tid >> 6;
    int wr = wid >> 1, wc = wid & 1;
    int lr = lane & 15, lq = lane >> 4;

    // staging: A 64x32 (1 u16x8/thread), B 128x32 (2 u16x8/thread)
    int arow = tid >> 2, aseg = (tid & 3) * 8;
    int brw = tid >> 1, bseg = (tid & 1) * 16;
    const unsigned short* gA = A + (size_t)(brow + arow) * K + aseg;
    const unsigned short* gB = Bt + (size_t)(bcol + brw) * K + bseg;
    bool aok = (brow + arow) < M;
    const u16x8 zz = {0, 0, 0, 0, 0, 0, 0, 0};

    u16x8 ra0 = aok ? *(const u16x8*)(gA) : zz;
    u16x8 rb0 = *(const u16x8*)(gB);
    u16x8 rb1 = *(const u16x8*)(gB + 8);

    f32x4 acc[2][4];
    #pragma unroll
    for (int i = 0; i < 2; i++)
        #pragma unroll
        for (int j = 0; j < 4; j++) acc[i][j] = (f32x4){0.f, 0.f, 0.f, 0.f};

    int nk = K >> 5;
    for (int ks = 0; ks < nk; ks++) {
        if (ks) __syncthreads();
        *(u16x8*)(As + arow * 40 + aseg) = ra0;
        *(u16x8*)(Bs + brw * 40 + bseg) = rb0;
        *(u16x8*)(Bs + brw * 40 + bseg + 8) = rb1;
        __syncthreads();
        if (ks + 1 < nk) {
            const unsigned short* pa = gA + (ks + 1) * 32;
            const unsigned short* pb = gB + (ks + 1) * 32;
            ra0 = aok ? *(const u16x8*)(pa) : zz;
            rb0 = *(const u16x8*)(pb);
            rb1 = *(const u16x8*)(pb + 8);
        }
        bf16x8 af[2], bfr[4];
        #pragma unroll
        for (int f = 0; f < 2; f++)
            af[f] = *(const bf16x8*)(As + (wr * 32 + f * 16 + lr) * 40 + lq * 8);
        #pragma unroll
        for (int f = 0; f < 4; f++)
            bfr[f] = *(const bf16x8*)(Bs + (wc * 64 + f * 16 + lr) * 40 + lq * 8);
        #pragma unroll
        for (int i = 0; i < 2; i++)
            #pragma unroll
            for (int j = 0; j < 4; j++)
                acc[i][j] = __builtin_amdgcn_mfma_f32_16x16x32_bf16(af[i], bfr[j], acc[i][j], 0, 0, 0);
    }

    __syncthreads();   // MFMA LDS reads done before SH reuse

    float bb[4];
    #pragma unroll
    for (int j = 0; j < 4; j++) bb[j] = bias[bcol + wc * 64 + j * 16 + lr];
    // each wave writes its 32x64 region of the 64x128 bounce tile (disjoint)
    #pragma unroll
    for (int i = 0; i < 2; i++)
        #pragma unroll
        for (int j = 0; j < 4; j++)
            #pragma unroll
            for (int r = 0; r < 4; r++) {
                int lrow = wr * 32 + i * 16 + lq * 4 + r;
                int col = wc * 64 + j * 16 + lr;
                SH[lrow * 136 + col] = f2bf(acc[i][j][r] + bb[j]);
            }
    __syncthreads();
    int row = tid >> 2;
    int ch = (tid & 3) * 32;
    int grow = brow + row;
    if (grow < M) {
        unsigned short* dstp = C + (size_t)grow * 256 + bcol + ch;
        const unsigned short* srcp = SH + row * 136 + ch;
        #pragma unroll
        for (int k = 0; k < 4; k++)
            *(u16x8*)(dstp + k * 8) = *(const u16x8*)(srcp + k * 8);
    }
}

// ---------------- bf16 MFMA GEMM v7 (QKV GEMM): 128x128, reg-staged, bounce epilogue ----------------
// MODE 3: colT<6 -> bf16 QKV + bias (NC=768); colT>=6 -> f32 skip C2 + bias (direct)
template<int MODE>
__global__ __launch_bounds__(256) void k_gemm7(const unsigned short* __restrict__ A,
                                               const unsigned short* __restrict__ Bt,
                                               const float* __restrict__ bias,
                                               unsigned short* __restrict__ C, float* __restrict__ C2,
                                               int M, int K, int nct, int q, int rr) {
    __shared__ __align__(16) unsigned short SH[10240];
    unsigned short* As = SH;
    unsigned short* Bs = SH + 5120;

    int bid = blockIdx.x;
    int xcd = bid & 7, idx = bid >> 3;
    int base = (xcd < rr) ? xcd * (q + 1) : rr * (q + 1) + (xcd - rr) * q;
    int nid = base + idx;
    int rowT = nid / nct, colT = nid - rowT * nct;
    int brow = rowT * 128, bcol = colT * 128;

    int tid = threadIdx.x;
    int lane = tid & 63, wid = tid >> 6;
    int wr = wid >> 1, wc = wid & 1;
    int lr = lane & 15, lq = lane >> 4;

    int srow = tid >> 1;
    int sseg = (tid & 1) * 16;
    const unsigned short* gA = A + (size_t)(brow + srow) * K + sseg;
    const unsigned short* gB = Bt + (size_t)(bcol + srow) * K + sseg;
    bool aok = (brow + srow) < M;
    const u16x8 zz = {0, 0, 0, 0, 0, 0, 0, 0};

    u16x8 ra0 = aok ? *(const u16x8*)(gA) : zz;
    u16x8 ra1 = aok ? *(const u16x8*)(gA + 8) : zz;
    u16x8 rb0 = *(const u16x8*)(gB);
    u16x8 rb1 = *(const u16x8*)(gB + 8);

    f32x4 acc[4][4];
    #pragma unroll
    for (int i = 0; i < 4; i++)
        #pragma unroll
        for (int j = 0; j < 4; j++) acc[i][j] = (f32x4){0.f, 0.f, 0.f, 0.f};

    int nk = K >> 5;
    for (int ks = 0; ks < nk; ks++) {
        if (ks) __syncthreads();
        *(u16x8*)(As + srow * 40 + sseg) = ra0;
        *(u16x8*)(As + srow * 40 + sseg + 8) = ra1;
        *(u16x8*)(Bs + srow * 40 + sseg) = rb0;
        *(u16x8*)(Bs + srow * 40 + sseg + 8) = rb1;
        __syncthreads();
        if (ks + 1 < nk) {
            const unsigned short* pa = gA + (ks + 1) * 32;
            const unsigned short* pb = gB + (ks + 1) * 32;
            ra0 = aok ? *(const u16x8*)(pa) : zz;
            ra1 = aok ? *(const u16x8*)(pa + 8) : zz;
            rb0 = *(const u16x8*)(pb);
            rb1 = *(const u16x8*)(pb + 8);
        }
        bf16x8 af[4], bfr[4];
        #pragma unroll
        for (int f = 0; f < 4; f++) {
            af[f] = *(const bf16x8*)(As + (wr * 64 + f * 16 + lr) * 40 + lq * 8);
            bfr[f] = *(const bf16x8*)(Bs + (wc * 64 + f * 16 + lr) * 40 + lq * 8);
        }
        #pragma unroll
        for (int i = 0; i < 4; i++)
            #pragma unroll
            for (int j = 0; j < 4; j++)
                acc[i][j] = __builtin_amdgcn_mfma_f32_16x16x32_bf16(af[i], bfr[j], acc[i][j], 0, 0, 0);
    }

    __syncthreads();

    bool bf16out = (colT < 6);
    if (bf16out) {
        float bb[4];
        #pragma unroll
        for (int j = 0; j < 4; j++) bb[j] = bias[bcol + wc * 64 + j * 16 + lr];
        const int NC = 768;
        #pragma unroll
        for (int h = 0; h < 2; h++) {
            if (h) __syncthreads();
            if (wr == h) {
                #pragma unroll
                for (int i = 0; i < 4; i++)
                    #pragma unroll
                    for (int j = 0; j < 4; j++)
                        #pragma unroll
                        for (int r = 0; r < 4; r++) {
                            int lrow2 = i * 16 + lq * 4 + r;
                            int col = wc * 64 + j * 16 + lr;
                            SH[lrow2 * 136 + col] = f2bf(acc[i][j][r] + bb[j]);
                        }
            }
            __syncthreads();
            int row = tid >> 2;
            int ch = (tid & 3) * 32;
            int grow = brow + h * 64 + row;
            if (grow < M) {
                unsigned short* dstp = C + (size_t)grow * NC + bcol + ch;
                const unsigned short* srcp = SH + row * 136 + ch;
                #pragma unroll
                for (int k = 0; k < 4; k++)
                    *(u16x8*)(dstp + k * 8) = *(const u16x8*)(srcp + k * 8);
            }
        }
    } else {
        #pragma unroll
        for (int i = 0; i < 4; i++) {
            int row = brow + wr * 64 + i * 16 + lq * 4;
            #pragma unroll
            for (int j = 0; j < 4; j++) {
                int col = bcol + wc * 64 + j * 16 + lr;
                #pragma unroll
                for (int r = 0; r < 4; r++) {
                    int gr = row + r;
                    if (gr >= M) continue;
                    C2[(size_t)gr * 256 + (col - 768)] = acc[i][j][r] + bias[col];
                }
            }
        }
    }
}

// ---------------- fused attention: one wave per node, online softmax, edges batched x8 ----------------
__global__ __launch_bounds__(256) void k_attn(const unsigned short* __restrict__ QKV, const int* __restrict__ csr,
                                              const int* __restrict__ start2, const int* __restrict__ deg,
                                              float* __restrict__ out) {
    int node = blockIdx.x * 4 + (threadIdx.x >> 6);
    int lane = threadIdx.x & 63;
    if (node >= NNODES) return;
    int s0 = start2[node * 8], n = deg[node];
    if (n == 0) return;
    ushort4 qu = *(const ushort4*)(QKV + (size_t)node * 768 + lane * 4);
    float q0 = bf2f(qu.x), q1 = bf2f(qu.y), q2 = bf2f(qu.z), q3 = bf2f(qu.w);
    float m = -INFINITY, den = 0.f;
    float4 acc = make_float4(0.f, 0.f, 0.f, 0.f);
    int j = 0;
    for (; j + 8 <= n; j += 8) {
        int sidx[8];
        #pragma unroll
        for (int t = 0; t < 8; t++) sidx[t] = csr[s0 + j + t];
        ushort4 kk[8], vv[8];
        #pragma unroll
        for (int t = 0; t < 8; t++) {
            const unsigned short* bp = QKV + (size_t)sidx[t] * 768;
            kk[t] = *(const ushort4*)(bp + 256 + lane * 4);
            vv[t] = *(const ushort4*)(bp + 512 + lane * 4);
        }
        float p[8];
        #pragma unroll
        for (int t = 0; t < 8; t++)
            p[t] = q0 * bf2f(kk[t].x) + q1 * bf2f(kk[t].y) + q2 * bf2f(kk[t].z) + q3 * bf2f(kk[t].w);
        #pragma unroll
        for (int o = 32; o; o >>= 1) {
            #pragma unroll
            for (int t = 0; t < 8; t++) p[t] += __shfl_xor(p[t], o);
        }
        float pm = p[0];
        #pragma unroll
        for (int t = 1; t < 8; t++) pm = fmaxf(pm, p[t]);
        pm *= 0.0625f;
        if (pm > m) {
            float rr = __expf(m - pm);   // first batch: exp(-inf)=0
            den *= rr;
            acc.x *= rr; acc.y *= rr; acc.z *= rr; acc.w *= rr;
            m = pm;
        }
        #pragma unroll
        for (int t = 0; t < 8; t++) {
            float e = __expf(p[t] * 0.0625f - m);
            den += e;
            acc.x += e * bf2f(vv[t].x);
            acc.y += e * bf2f(vv[t].y);
            acc.z += e * bf2f(vv[t].z);
            acc.w += e * bf2f(vv[t].w);
        }
    }
    for (; j < n; j++) {
        const unsigned short* basep = QKV + (size_t)csr[s0 + j] * 768;
        ushort4 ku = *(const ushort4*)(basep + 256 + lane * 4);
        ushort4 vu = *(const ushort4*)(basep + 512 + lane * 4);
        float p = q0 * bf2f(ku.x) + q1 * bf2f(ku.y) + q2 * bf2f(ku.z) + q3 * bf2f(ku.w);
        #pragma unroll
        for (int o = 32; o; o >>= 1) p += __shfl_xor(p, o);
        p *= 0.0625f;
        if (p > m) {
            float rr = __expf(m - p);
            den *= rr;
            acc.x *= rr; acc.y *= rr; acc.z *= rr; acc.w *= rr;
            m = p;
        }
        float ex = __expf(p - m);
        den += ex;
        acc.x += ex * bf2f(vu.x); acc.y += ex * bf2f(vu.y);
        acc.z += ex * bf2f(vu.z); acc.w += ex * bf2f(vu.w);
    }
    float rinv = 1.0f / fmaxf(den, 1e-16f);
    float4* o4 = (float4*)(out + (size_t)node * 256);
    float4 o = o4[lane];
    o.x += acc.x * rinv; o.y += acc.y * rinv; o.z += acc.z * rinv; o.w += acc.w * rinv;
    o4[lane] = o;
}

// ---------------- batch norm + leaky relu ----------------
__global__ __launch_bounds__(256) void k_bnstats(const float* __restrict__ out, float* __restrict__ sums,
                                                 float* __restrict__ sumsq) {
    int c = threadIdx.x;
    int rows_per = (NNODES + gridDim.x - 1) / gridDim.x;
    int r0 = blockIdx.x * rows_per;
    int r1 = r0 + rows_per; if (r1 > NNODES) r1 = NNODES;
    float s = 0.f, ss = 0.f;
    for (int r = r0; r < r1; r++) {
        float v = out[(size_t)r * 256 + c];
        s += v; ss += v * v;
    }
    atomicAdd(&sums[c], s);
    atomicAdd(&sumsq[c], ss);
}

__global__ __launch_bounds__(256) void k_bnapply(float4* __restrict__ out, const float* __restrict__ sums,
                                                 const float* __restrict__ sumsq, const float* __restrict__ gamma,
                                                 const float* __restrict__ beta) {
    int i = blockIdx.x * 256 + threadIdx.x;
    if (i >= NNODES * 64) return;
    int c4 = i & 63;
    float4 sc, sh;
    #pragma unroll
    for (int t = 0; t < 4; t++) {
        int c = c4 * 4 + t;
        float mu = sums[c] * (1.0f / NNODES);
        float var = sumsq[c] * (1.0f / NNODES) - mu * mu;
        float s = gamma[c] * rsqrtf(fmaxf(var, 0.f) + EPSBN);
        ((float*)&sc)[t] = s;
        ((float*)&sh)[t] = beta[c] - mu * s;
    }
    float4 v = out[i];
    v.x = v.x * sc.x + sh.x; v.y = v.y * sc.y + sh.y;
    v.z = v.z * sc.z + sh.z; v.w = v.w * sc.w + sh.w;
    v.x = v.x > 0.f ? v.x : 0.01f * v.x;
    v.y = v.y > 0.f ? v.y : 0.01f * v.y;
    v.z = v.z > 0.f ? v.z : 0.01f * v.z;
    v.w = v.w > 0.f ? v.w : 0.01f * v.w;
    out[i] = v;
}

extern "C" void kernel_launch(void* const* d_in, const int* in_sizes, int n_in,
                              void* d_out, int out_size, void* d_ws, size_t ws_size,
                              hipStream_t stream) {
    const float* x = (const float*)d_in[0];
    const int* ei = (const int*)d_in[1];
    const int* etype = (const int*)d_in[2];
    const float* Wrel = (const float*)d_in[3];
    const float* Wroot = (const float*)d_in[4];
    const float* b1 = (const float*)d_in[5];
    const float* Wq = (const float*)d_in[6];
    const float* bq = (const float*)d_in[7];
    const float* Wk = (const float*)d_in[8];
    const float* bk = (const float*)d_in[9];
    const float* Wv = (const float*)d_in[10];
    const float* bv = (const float*)d_in[11];
    const float* Ws = (const float*)d_in[12];
    const float* bs = (const float*)d_in[13];
    const float* gamma = (const float*)d_in[14];
    const float* beta = (const float*)d_in[15];
    float* out = (float*)d_out;

    const int* srcA = ei;
    const int* dstA = ei + NEDGES;

    char* w = (char*)d_ws;
    unsigned short* S = (unsigned short*)w;     w += (size_t)NNODES * 2304 * 2;
    unsigned short* x_bf = (unsigned short*)w;  w += (size_t)NNODES * 256 * 2;
    unsigned short* x1bf = (unsigned short*)w;  w += (size_t)NNODES * 256 * 2;
    unsigned short* QKVbf = (unsigned short*)w; w += (size_t)NNODES * 768 * 2;
    unsigned short* BtA = (unsigned short*)w;   w += (size_t)256 * 2304 * 2;
    unsigned short* B2t = (unsigned short*)w;   w += (size_t)1024 * 256 * 2;
    float* bias2 = (float*)w;                   w += 1024 * 4;
    int* cnt = (int*)w;                         w += (size_t)NNODES * RREL * 4;
    int* deg = (int*)w;                         w += (size_t)NNODES * 4;
    int* startv = (int*)w;                      w += (size_t)NNODES * 4;
    int* start2 = (int*)w;                      w += (size_t)NNODES * RREL * 4;
    int* cursor2 = (int*)w;                     w += (size_t)NNODES * RREL * 4;
    int* csr = (int*)w;                         w += (size_t)NEDGES * 4;
    float* sums = (float*)w;                    w += 1024;
    float* sumsq = (float*)w;                   w += 1024;
    size_t need = (size_t)(w - (char*)d_ws);
    if (ws_size < need) return;

    hipMemsetAsync(cnt, 0, (size_t)NNODES * RREL * 4, stream);
    hipMemsetAsync(sums, 0, 2048, stream);

    k_count<<<(NEDGES + 255) / 256, 256, 0, stream>>>(dstA, etype, cnt);
    k_deg<<<(NNODES + 255) / 256, 256, 0, stream>>>(cnt, deg);
    k_scan<<<1, 256, 0, stream>>>(deg, startv);
    k_sub<<<(NNODES + 255) / 256, 256, 0, stream>>>(cnt, startv, start2, cursor2);
    k_fill<<<(NEDGES + 255) / 256, 256, 0, stream>>>(srcA, dstA, etype, cursor2, csr);

    k_prep<<<(PR0 + PR1 + PR2 + PR3) / 256, 256, 0, stream>>>(x, Wrel, Wroot, Wq, Wk, Wv, Ws,
                                                              bq, bk, bv, bs, x_bf, BtA, B2t, bias2);

    // S[d] = [mean_r(x) | x] (bf16)
    k_mean<<<(NNODES + 3) / 4, 256, 0, stream>>>(x_bf, csr, start2, cnt, S);

    // x1bf = bf16(S @ [W_0..W_7; W_root] + b1); K=2304, 64x128 tiles: 313x2 = 626 blocks
    {
        int nwg = 313 * 2;
        int q = nwg / 8, rr = nwg % 8;
        k_gemm8<<<nwg, 256, 0, stream>>>(S, BtA, b1, x1bf, NNODES, 2304, 2, q, rr);
    }

    // [q|k|v -> QKVbf, skip -> out] = x1 @ [Wq|Wk|Wv|Wskip] + bias2; K=256, 157x8
    {
        int nwg = 157 * 8;
        int q = nwg / 8, rr = nwg % 8;
        k_gemm7<3><<<nwg, 256, 0, stream>>>(x1bf, B2t, bias2, QKVbf, out, NNODES, 256, 8, q, rr);
    }

    k_attn<<<(NNODES + 3) / 4, 256, 0, stream>>>(QKVbf, csr, start2, deg, out);

    k_bnstats<<<400, 256, 0, stream>>>(out, sums, sumsq);
    k_bnapply<<<(NNODES * 64 + 255) / 256, 256, 0, stream>>>((float4*)out, sums, sumsq, gamma, beta);
}